// Round 1
// baseline (325.559 us; speedup 1.0000x reference)
//
#include <hip/hip_runtime.h>
#include <hip/hip_bf16.h>

// MoE: T=2048 tokens, D=1024, E=8 routed experts (H=768, top-2), NS=2 shared (H_s=1536 eff)
// Strategy: fp32 gate (exact top-k), bf16 MFMA GEMMs for fc1 (fused silu+route-scale)
// and fc2 (single K=7680 GEMM over concatenated expert/shared acts).

typedef short bf16x8 __attribute__((ext_vector_type(8)));
typedef float f32x4 __attribute__((ext_vector_type(4)));

#define T_TOK 2048
#define KACT  7680   // 8*768 routed + 1536 shared act columns

__device__ __forceinline__ unsigned short f2b(float f) {
    __hip_bfloat16 h = __float2bfloat16(f);
    return *reinterpret_cast<unsigned short*>(&h);
}

__device__ __forceinline__ void ldst16(const unsigned short* g, unsigned short* l) {
    __builtin_amdgcn_global_load_lds(
        (const __attribute__((address_space(1))) unsigned int*)g,
        (__attribute__((address_space(3))) unsigned int*)l, 16, 0, 0);
}

// ---------------- conversions ----------------
__global__ __launch_bounds__(256) void k_f2b8(const float* __restrict__ src,
                                              unsigned short* __restrict__ dst, int n8) {
    int i = blockIdx.x * blockDim.x + threadIdx.x;
    if (i >= n8) return;
    const float4* s = reinterpret_cast<const float4*>(src) + (size_t)i * 2;
    float4 v0 = s[0], v1 = s[1];
    union { unsigned short u[8]; uint4 v; } o;
    o.u[0]=f2b(v0.x); o.u[1]=f2b(v0.y); o.u[2]=f2b(v0.z); o.u[3]=f2b(v0.w);
    o.u[4]=f2b(v1.x); o.u[5]=f2b(v1.y); o.u[6]=f2b(v1.z); o.u[7]=f2b(v1.w);
    reinterpret_cast<uint4*>(dst)[i] = o.v;
}

// W2[e][d][h] (fp32) -> W2b[d][e*768+h] (bf16)
__global__ __launch_bounds__(256) void k_w2r(const float* __restrict__ W2,
                                             unsigned short* __restrict__ W2b, int total8) {
    int i = blockIdx.x * blockDim.x + threadIdx.x;
    if (i >= total8) return;                     // total8 = 8*1024*96
    int h8 = i % 96, d = (i / 96) % 1024, e = i / (96 * 1024);
    const float4* s = reinterpret_cast<const float4*>(W2 + ((size_t)(e*1024+d))*768 + h8*8);
    float4 v0 = s[0], v1 = s[1];
    union { unsigned short u[8]; uint4 v; } o;
    o.u[0]=f2b(v0.x); o.u[1]=f2b(v0.y); o.u[2]=f2b(v0.z); o.u[3]=f2b(v0.w);
    o.u[4]=f2b(v1.x); o.u[5]=f2b(v1.y); o.u[6]=f2b(v1.z); o.u[7]=f2b(v1.w);
    *reinterpret_cast<uint4*>(W2b + (size_t)d*KACT + e*768 + h8*8) = o.v;
}

// Ws2[d][h'] (fp32, 1024x1536) -> W2b[d][6144+h'] (bf16)
__global__ __launch_bounds__(256) void k_w2s(const float* __restrict__ Ws2,
                                             unsigned short* __restrict__ W2b, int total8) {
    int i = blockIdx.x * blockDim.x + threadIdx.x;
    if (i >= total8) return;                     // total8 = 1024*192
    int h8 = i % 192, d = i / 192;
    const float4* s = reinterpret_cast<const float4*>(Ws2 + (size_t)d*1536 + h8*8);
    float4 v0 = s[0], v1 = s[1];
    union { unsigned short u[8]; uint4 v; } o;
    o.u[0]=f2b(v0.x); o.u[1]=f2b(v0.y); o.u[2]=f2b(v0.z); o.u[3]=f2b(v0.w);
    o.u[4]=f2b(v1.x); o.u[5]=f2b(v1.y); o.u[6]=f2b(v1.z); o.u[7]=f2b(v1.w);
    *reinterpret_cast<uint4*>(W2b + (size_t)d*KACT + 6144 + h8*8) = o.v;
}

// ---------------- gate: fp32 logits, softmax, top-2 -> dense weights [T][8] ----------------
__global__ __launch_bounds__(256) void k_gate(const float* __restrict__ x,
                                              const float* __restrict__ gw,
                                              float* __restrict__ wdense) {
    int t = blockIdx.x;
    int lane = threadIdx.x & 63, w = threadIdx.x >> 6;
    __shared__ float sc[8];
    const float* xr = x + (size_t)t * 1024;
    for (int e = w; e < 8; e += 4) {
        const float* g = gw + (size_t)e * 1024;
        float s = 0.f;
        for (int k = lane; k < 1024; k += 64) s += xr[k] * g[k];
        for (int off = 32; off > 0; off >>= 1) s += __shfl_down(s, off, 64);
        if (lane == 0) sc[e] = s;
    }
    __syncthreads();
    if (threadIdx.x == 0) {
        float m = sc[0];
        for (int e = 1; e < 8; e++) m = fmaxf(m, sc[e]);
        float ex[8], sum = 0.f;
        for (int e = 0; e < 8; e++) { ex[e] = expf(sc[e] - m); sum += ex[e]; }
        float inv = 1.f / sum;
        int i1 = 0;
        for (int e = 1; e < 8; e++) if (sc[e] > sc[i1]) i1 = e;
        int i2 = -1; float s2 = -1e30f;
        for (int e = 0; e < 8; e++) if (e != i1 && sc[e] > s2) { s2 = sc[e]; i2 = e; }
        float wv[8];
        for (int e = 0; e < 8; e++) wv[e] = 0.f;
        wv[i1] = ex[i1] * inv; wv[i2] = ex[i2] * inv;
        for (int e = 0; e < 8; e++) wdense[t * 8 + e] = wv[e];
    }
}

// ---------------- fc1: act[t][ac] = w(t,e) * y * silu(g), bf16 MFMA ----------------
// block: M=128 tokens x 64 act cols (needs 128 B rows: 64 y + 64 g). BK=32.
__global__ __launch_bounds__(256) void k_fc1(const unsigned short* __restrict__ xb,
                                             const unsigned short* __restrict__ W1b,
                                             const unsigned short* __restrict__ Ws1b,
                                             const float* __restrict__ wdense,
                                             unsigned short* __restrict__ act) {
    __shared__ alignas(16) unsigned short As[128 * 32];
    __shared__ alignas(16) unsigned short Bs[128 * 32];
    const int tid = threadIdx.x;
    const int lane = tid & 63, w = tid >> 6;
    const int wr = w >> 1, wc = w & 1;
    const int m0 = blockIdx.x * 128;
    const int ac0 = blockIdx.y * 64;

    const unsigned short* B;
    int offY, offG, e = 0, routed;
    if (ac0 < 6144) {
        e = ac0 / 768; int h0 = ac0 % 768;
        B = W1b + (size_t)e * 1536 * 1024;
        offY = h0 * 1024; offG = (h0 + 768 - 64) * 1024; routed = 1;
    } else {
        int h0 = ac0 - 6144;
        B = Ws1b;
        offY = h0 * 1024; offG = (h0 + 1536 - 64) * 1024; routed = 0;
    }

    f32x4 accy[4][2], accg[4][2];
    for (int i = 0; i < 4; i++)
        for (int j = 0; j < 2; j++) {
            accy[i][j] = (f32x4){0.f, 0.f, 0.f, 0.f};
            accg[i][j] = (f32x4){0.f, 0.f, 0.f, 0.f};
        }

    for (int k0 = 0; k0 < 1024; k0 += 32) {
        // stage A: 128x32 bf16 = 512 chunks of 16B, 2/thread
        for (int q = 0; q < 2; q++) {
            int c = q * 256 + tid;
            int row = c >> 2, k8 = c & 3;
            ldst16(xb + (size_t)(m0 + row) * 1024 + k0 + k8 * 8, As + c * 8);
        }
        // stage B: rows 0..63 = y rows, 64..127 = g rows (no divergence: q=0 all y, q=1 all g)
        for (int q = 0; q < 2; q++) {
            int c = q * 256 + tid;
            int row = c >> 2, k8 = c & 3;
            int off = (row < 64) ? offY : offG;
            ldst16(B + (size_t)off + (size_t)row * 1024 + k0 + k8 * 8, Bs + c * 8);
        }
        __syncthreads();
        {
            const int ko = (lane >> 4) * 8;
            bf16x8 a[4], by[2], bg[2];
            for (int i = 0; i < 4; i++)
                a[i] = *(const bf16x8*)&As[(64 * wr + 16 * i + (lane & 15)) * 32 + ko];
            for (int j = 0; j < 2; j++) {
                by[j] = *(const bf16x8*)&Bs[(32 * wc + 16 * j + (lane & 15)) * 32 + ko];
                bg[j] = *(const bf16x8*)&Bs[(64 + 32 * wc + 16 * j + (lane & 15)) * 32 + ko];
            }
            for (int i = 0; i < 4; i++)
                for (int j = 0; j < 2; j++) {
                    accy[i][j] = __builtin_amdgcn_mfma_f32_16x16x32_bf16(a[i], by[j], accy[i][j], 0, 0, 0);
                    accg[i][j] = __builtin_amdgcn_mfma_f32_16x16x32_bf16(a[i], bg[j], accg[i][j], 0, 0, 0);
                }
        }
        __syncthreads();
    }

    // epilogue: act = scale * y * silu(g); C/D map: col=lane&15, row=(lane>>4)*4+reg
    for (int i = 0; i < 4; i++) {
        for (int r = 0; r < 4; r++) {
            int trow = m0 + 64 * wr + 16 * i + ((lane >> 4) << 2) + r;
            float scale = routed ? wdense[trow * 8 + e] : 1.0f;
            for (int j = 0; j < 2; j++) {
                float y = accy[i][j][r];
                float g = accg[i][j][r];
                float sg = g / (1.0f + __expf(-g));
                act[(size_t)trow * KACT + ac0 + 32 * wc + 16 * j + (lane & 15)] = f2b(scale * y * sg);
            }
        }
    }
}

// ---------------- fc2: out[T][1024] = act[T][7680] @ W2b[1024][7680]^T ----------------
// block: 64x64 tile, BK=32, waves 2x2 each 32x32.
__global__ __launch_bounds__(256) void k_fc2(const unsigned short* __restrict__ act,
                                             const unsigned short* __restrict__ W2b,
                                             float* __restrict__ out) {
    __shared__ alignas(16) unsigned short As[64 * 32];
    __shared__ alignas(16) unsigned short Bs[64 * 32];
    const int tid = threadIdx.x;
    const int lane = tid & 63, w = tid >> 6;
    const int wr = w >> 1, wc = w & 1;
    const int m0 = blockIdx.x * 64, n0 = blockIdx.y * 64;

    f32x4 acc[2][2];
    for (int i = 0; i < 2; i++)
        for (int j = 0; j < 2; j++) acc[i][j] = (f32x4){0.f, 0.f, 0.f, 0.f};

    for (int k0 = 0; k0 < KACT; k0 += 32) {
        {
            int c = tid;                 // 256 chunks of 16B each for A and B
            int row = c >> 2, k8 = c & 3;
            ldst16(act + (size_t)(m0 + row) * KACT + k0 + k8 * 8, As + c * 8);
            ldst16(W2b + (size_t)(n0 + row) * KACT + k0 + k8 * 8, Bs + c * 8);
        }
        __syncthreads();
        {
            const int ko = (lane >> 4) * 8;
            bf16x8 a[2], b[2];
            for (int i = 0; i < 2; i++)
                a[i] = *(const bf16x8*)&As[(32 * wr + 16 * i + (lane & 15)) * 32 + ko];
            for (int j = 0; j < 2; j++)
                b[j] = *(const bf16x8*)&Bs[(32 * wc + 16 * j + (lane & 15)) * 32 + ko];
            for (int i = 0; i < 2; i++)
                for (int j = 0; j < 2; j++)
                    acc[i][j] = __builtin_amdgcn_mfma_f32_16x16x32_bf16(a[i], b[j], acc[i][j], 0, 0, 0);
        }
        __syncthreads();
    }

    for (int i = 0; i < 2; i++)
        for (int j = 0; j < 2; j++)
            for (int r = 0; r < 4; r++) {
                int trow = m0 + 32 * wr + 16 * i + ((lane >> 4) << 2) + r;
                int col = n0 + 32 * wc + 16 * j + (lane & 15);
                out[(size_t)trow * 1024 + col] = acc[i][j][r];
            }
}

extern "C" void kernel_launch(void* const* d_in, const int* in_sizes, int n_in,
                              void* d_out, int out_size, void* d_ws, size_t ws_size,
                              hipStream_t stream) {
    const float* x   = (const float*)d_in[0];
    const float* gw  = (const float*)d_in[1];
    const float* W1  = (const float*)d_in[2];
    const float* W2  = (const float*)d_in[3];
    const float* Ws1 = (const float*)d_in[4];
    const float* Ws2 = (const float*)d_in[5];
    float* out = (float*)d_out;

    char* ws = (char*)d_ws;
    unsigned short* xb     = (unsigned short*)(ws);                       // 2048*1024
    unsigned short* W1b    = (unsigned short*)(ws + 4194304);             // 8*1536*1024
    unsigned short* Ws1b   = (unsigned short*)(ws + 29360128);            // 3072*1024
    unsigned short* W2b    = (unsigned short*)(ws + 35651584);            // 1024*7680
    unsigned short* actbuf = (unsigned short*)(ws + 51380224);            // 2048*7680
    float* wdense          = (float*)(ws + 82837504);                     // 2048*8

    // conversions
    k_f2b8<<<(262144 + 255) / 256, 256, 0, stream>>>(x, xb, 262144);
    k_f2b8<<<(1572864 + 255) / 256, 256, 0, stream>>>(W1, W1b, 1572864);
    k_f2b8<<<(393216 + 255) / 256, 256, 0, stream>>>(Ws1, Ws1b, 393216);
    k_w2r<<<(786432 + 255) / 256, 256, 0, stream>>>(W2, W2b, 786432);
    k_w2s<<<(196608 + 255) / 256, 256, 0, stream>>>(Ws2, W2b, 196608);

    // gate (fp32 exact)
    k_gate<<<2048, 256, 0, stream>>>(x, gw, wdense);

    // fc1 + silu + route-scale -> act
    k_fc1<<<dim3(16, 120), 256, 0, stream>>>(xb, W1b, Ws1b, wdense, actbuf);

    // fc2 -> out
    k_fc2<<<dim3(32, 16), 256, 0, stream>>>(actbuf, W2b, out);
}

// Round 2
// 312.588 us; speedup vs baseline: 1.0415x; 1.0415x over previous
//
#include <hip/hip_runtime.h>
#include <hip/hip_bf16.h>

// Sparse MoE: T=2048, D=1024, E=8 routed (H=768, top-2), shared GatedMLP (1536 hidden).
// R2: counting-sort routing -> per-expert gathered GEMMs (2.5x FLOP cut vs dense),
// single fused conversion kernel, BK=64 fc2 tiles, XOR-swizzled LDS (source-side).

typedef short bf16x8 __attribute__((ext_vector_type(8)));
typedef float f32x4 __attribute__((ext_vector_type(4)));

__device__ __forceinline__ unsigned short f2b(float f) {
    __hip_bfloat16 h = __float2bfloat16(f);
    return *reinterpret_cast<unsigned short*>(&h);
}

__device__ __forceinline__ void ldst16(const unsigned short* g, unsigned short* l) {
    __builtin_amdgcn_global_load_lds(
        (const __attribute__((address_space(1))) unsigned int*)g,
        (__attribute__((address_space(3))) unsigned int*)l, 16, 0, 0);
}

__device__ __forceinline__ void cvt8(const float* s, unsigned short* d, int j) {
    const float4* sp = reinterpret_cast<const float4*>(s) + (size_t)j * 2;
    float4 v0 = sp[0], v1 = sp[1];
    union { unsigned short u[8]; uint4 v; } o;
    o.u[0]=f2b(v0.x); o.u[1]=f2b(v0.y); o.u[2]=f2b(v0.z); o.u[3]=f2b(v0.w);
    o.u[4]=f2b(v1.x); o.u[5]=f2b(v1.y); o.u[6]=f2b(v1.z); o.u[7]=f2b(v1.w);
    *(reinterpret_cast<uint4*>(d) + j) = o.v;
}

// ---------------- one-shot fp32->bf16 conversion of all tensors ----------------
__global__ __launch_bounds__(256) void k_conv(const float* __restrict__ x,
                                              const float* __restrict__ W1,
                                              const float* __restrict__ Ws1,
                                              const float* __restrict__ W2,
                                              const float* __restrict__ Ws2,
                                              unsigned short* __restrict__ xb,
                                              unsigned short* __restrict__ W1b,
                                              unsigned short* __restrict__ Ws1b,
                                              unsigned short* __restrict__ W2b,
                                              unsigned short* __restrict__ Ws2b) {
    int i = blockIdx.x * 256 + threadIdx.x;
    if (i < 262144)        cvt8(x,   xb,   i);
    else if (i < 1835008)  cvt8(W1,  W1b,  i - 262144);
    else if (i < 2228224)  cvt8(Ws1, Ws1b, i - 1835008);
    else if (i < 3014656)  cvt8(W2,  W2b,  i - 2228224);
    else if (i < 3211264)  cvt8(Ws2, Ws2b, i - 3014656);
}

// ---------------- gate: fp32 logits, softmax, top-2 ----------------
__global__ __launch_bounds__(256) void k_gate(const float* __restrict__ x,
                                              const float* __restrict__ gw,
                                              int* __restrict__ topk_e,
                                              float* __restrict__ topk_w) {
    int t = blockIdx.x;
    int lane = threadIdx.x & 63, w = threadIdx.x >> 6;
    __shared__ float sc[8];
    const float* xr = x + (size_t)t * 1024;
    for (int e = w; e < 8; e += 4) {
        const float* g = gw + (size_t)e * 1024;
        float s = 0.f;
        for (int k = lane; k < 1024; k += 64) s += xr[k] * g[k];
        for (int off = 32; off > 0; off >>= 1) s += __shfl_down(s, off, 64);
        if (lane == 0) sc[e] = s;
    }
    __syncthreads();
    if (threadIdx.x == 0) {
        float m = sc[0];
        for (int e = 1; e < 8; e++) m = fmaxf(m, sc[e]);
        float ex[8], sum = 0.f;
        for (int e = 0; e < 8; e++) { ex[e] = expf(sc[e] - m); sum += ex[e]; }
        float inv = 1.f / sum;
        int i1 = 0;
        for (int e = 1; e < 8; e++) if (sc[e] > sc[i1]) i1 = e;
        int i2 = -1; float s2 = -1e30f;
        for (int e = 0; e < 8; e++) if (e != i1 && sc[e] > s2) { s2 = sc[e]; i2 = e; }
        topk_e[t * 2]     = i1; topk_w[t * 2]     = ex[i1] * inv;
        topk_e[t * 2 + 1] = i2; topk_w[t * 2 + 1] = ex[i2] * inv;
    }
}

// ---------------- counting sort into per-expert lists ----------------
__global__ __launch_bounds__(256) void k_sort(const int* __restrict__ topk_e,
                                              const float* __restrict__ topk_w,
                                              int* __restrict__ tokslot,
                                              float* __restrict__ wroute,
                                              int* __restrict__ cnt) {
    __shared__ int lcnt[8], lcur[8];
    int tid = threadIdx.x;
    if (tid < 8) { lcnt[tid] = 0; lcur[tid] = 0; }
    __syncthreads();
    for (int i = tid; i < 4096; i += 256) atomicAdd(&lcnt[topk_e[i]], 1);
    __syncthreads();
    if (tid < 8) cnt[tid] = lcnt[tid];
    for (int i = tid; i < 4096; i += 256) {
        int e = topk_e[i];
        int pos = atomicAdd(&lcur[e], 1);
        tokslot[e * 2048 + pos] = i;          // i = t*2 + slot
        wroute[e * 2048 + pos]  = topk_w[i];
    }
}

// ---------------- routed fc1: gathered tokens, fused silu + route weight ----------------
// tile 128 tokens x 64 act cols, BK=32; B rows 0..63 = y, 64..127 = g.
__global__ __launch_bounds__(256) void k_fc1r(const unsigned short* __restrict__ xb,
                                              const unsigned short* __restrict__ W1b,
                                              const int* __restrict__ tokslot,
                                              const float* __restrict__ wroute,
                                              const int* __restrict__ cnt,
                                              unsigned short* __restrict__ act_r) {
    __shared__ alignas(16) unsigned short As[128 * 32];
    __shared__ alignas(16) unsigned short Bs[128 * 32];
    const int e = blockIdx.z;
    const int Te = cnt[e];
    const int m0 = blockIdx.x * 128;
    if (m0 >= Te) return;
    const int h0 = blockIdx.y * 64;
    const int tid = threadIdx.x, lane = tid & 63, w = tid >> 6;
    const int wr = w >> 1, wc = w & 1;

    const unsigned short* B = W1b + (size_t)e * 1536 * 1024;
    const int r0 = tid >> 2, r1 = 64 + (tid >> 2);     // LDS rows for this thread's chunks
    const int kc = tid & 3;
    const int kA0 = (kc ^ ((r0 >> 1) & 3)) * 8;
    const int kA1 = (kc ^ ((r1 >> 1) & 3)) * 8;
    const int t0 = (m0 + r0 < Te) ? (tokslot[e * 2048 + m0 + r0] >> 1) : 0;
    const int t1 = (m0 + r1 < Te) ? (tokslot[e * 2048 + m0 + r1] >> 1) : 0;
    const size_t offB0 = (size_t)(h0 + r0) * 1024;              // y
    const size_t offB1 = (size_t)(768 + h0 + (r1 - 64)) * 1024; // g

    f32x4 accy[4][2], accg[4][2];
    for (int i = 0; i < 4; i++)
        for (int j = 0; j < 2; j++) {
            accy[i][j] = (f32x4){0.f, 0.f, 0.f, 0.f};
            accg[i][j] = (f32x4){0.f, 0.f, 0.f, 0.f};
        }

    for (int k0 = 0; k0 < 1024; k0 += 32) {
        ldst16(xb + (size_t)t0 * 1024 + k0 + kA0, As + tid * 8);
        ldst16(xb + (size_t)t1 * 1024 + k0 + kA1, As + (256 + tid) * 8);
        ldst16(B + offB0 + k0 + kA0, Bs + tid * 8);
        ldst16(B + offB1 + k0 + kA1, Bs + (256 + tid) * 8);
        __syncthreads();
        {
            const int cq = lane >> 4;
            bf16x8 a[4], by[2], bg[2];
            for (int i = 0; i < 4; i++) {
                int r = 64 * wr + 16 * i + (lane & 15);
                a[i] = *(const bf16x8*)&As[r * 32 + ((cq ^ ((r >> 1) & 3)) << 3)];
            }
            for (int j = 0; j < 2; j++) {
                int ry = 32 * wc + 16 * j + (lane & 15);
                by[j] = *(const bf16x8*)&Bs[ry * 32 + ((cq ^ ((ry >> 1) & 3)) << 3)];
                int rg = 64 + ry;
                bg[j] = *(const bf16x8*)&Bs[rg * 32 + ((cq ^ ((rg >> 1) & 3)) << 3)];
            }
            for (int i = 0; i < 4; i++)
                for (int j = 0; j < 2; j++) {
                    accy[i][j] = __builtin_amdgcn_mfma_f32_16x16x32_bf16(a[i], by[j], accy[i][j], 0, 0, 0);
                    accg[i][j] = __builtin_amdgcn_mfma_f32_16x16x32_bf16(a[i], bg[j], accg[i][j], 0, 0, 0);
                }
        }
        __syncthreads();
    }

    for (int i = 0; i < 4; i++)
        for (int r = 0; r < 4; r++) {
            int irow = m0 + 64 * wr + 16 * i + ((lane >> 4) << 2) + r;
            if (irow >= Te) continue;
            float sw = wroute[e * 2048 + irow];
            for (int j = 0; j < 2; j++) {
                float y = accy[i][j][r], g = accg[i][j][r];
                float sg = g / (1.0f + __expf(-g));
                act_r[((size_t)e * 2048 + irow) * 768 + h0 + 32 * wc + 16 * j + (lane & 15)] =
                    f2b(sw * y * sg);
            }
        }
}

// ---------------- shared fc1 (dense), fused silu ----------------
__global__ __launch_bounds__(256) void k_fc1s(const unsigned short* __restrict__ xb,
                                              const unsigned short* __restrict__ Ws1b,
                                              unsigned short* __restrict__ act_s) {
    __shared__ alignas(16) unsigned short As[128 * 32];
    __shared__ alignas(16) unsigned short Bs[128 * 32];
    const int m0 = blockIdx.x * 128;
    const int h0 = blockIdx.y * 64;
    const int tid = threadIdx.x, lane = tid & 63, w = tid >> 6;
    const int wr = w >> 1, wc = w & 1;

    const int r0 = tid >> 2, r1 = 64 + (tid >> 2);
    const int kc = tid & 3;
    const int kA0 = (kc ^ ((r0 >> 1) & 3)) * 8;
    const int kA1 = (kc ^ ((r1 >> 1) & 3)) * 8;
    const size_t offB0 = (size_t)(h0 + r0) * 1024;
    const size_t offB1 = (size_t)(1536 + h0 + (r1 - 64)) * 1024;

    f32x4 accy[4][2], accg[4][2];
    for (int i = 0; i < 4; i++)
        for (int j = 0; j < 2; j++) {
            accy[i][j] = (f32x4){0.f, 0.f, 0.f, 0.f};
            accg[i][j] = (f32x4){0.f, 0.f, 0.f, 0.f};
        }

    for (int k0 = 0; k0 < 1024; k0 += 32) {
        ldst16(xb + (size_t)(m0 + r0) * 1024 + k0 + kA0, As + tid * 8);
        ldst16(xb + (size_t)(m0 + r1) * 1024 + k0 + kA1, As + (256 + tid) * 8);
        ldst16(Ws1b + offB0 + k0 + kA0, Bs + tid * 8);
        ldst16(Ws1b + offB1 + k0 + kA1, Bs + (256 + tid) * 8);
        __syncthreads();
        {
            const int cq = lane >> 4;
            bf16x8 a[4], by[2], bg[2];
            for (int i = 0; i < 4; i++) {
                int r = 64 * wr + 16 * i + (lane & 15);
                a[i] = *(const bf16x8*)&As[r * 32 + ((cq ^ ((r >> 1) & 3)) << 3)];
            }
            for (int j = 0; j < 2; j++) {
                int ry = 32 * wc + 16 * j + (lane & 15);
                by[j] = *(const bf16x8*)&Bs[ry * 32 + ((cq ^ ((ry >> 1) & 3)) << 3)];
                int rg = 64 + ry;
                bg[j] = *(const bf16x8*)&Bs[rg * 32 + ((cq ^ ((rg >> 1) & 3)) << 3)];
            }
            for (int i = 0; i < 4; i++)
                for (int j = 0; j < 2; j++) {
                    accy[i][j] = __builtin_amdgcn_mfma_f32_16x16x32_bf16(a[i], by[j], accy[i][j], 0, 0, 0);
                    accg[i][j] = __builtin_amdgcn_mfma_f32_16x16x32_bf16(a[i], bg[j], accg[i][j], 0, 0, 0);
                }
        }
        __syncthreads();
    }

    for (int i = 0; i < 4; i++)
        for (int r = 0; r < 4; r++) {
            int trow = m0 + 64 * wr + 16 * i + ((lane >> 4) << 2) + r;
            for (int j = 0; j < 2; j++) {
                float y = accy[i][j][r], g = accg[i][j][r];
                float sg = g / (1.0f + __expf(-g));
                act_s[(size_t)trow * 1536 + h0 + 32 * wc + 16 * j + (lane & 15)] = f2b(y * sg);
            }
        }
}

// ---------------- routed fc2: per-expert GEMM, scatter to part[t*2+slot] ----------------
// tile 64x64, BK=64, K=768.
__global__ __launch_bounds__(256) void k_fc2r(const unsigned short* __restrict__ act_r,
                                              const unsigned short* __restrict__ W2b,
                                              const int* __restrict__ tokslot,
                                              const int* __restrict__ cnt,
                                              float* __restrict__ part) {
    __shared__ alignas(16) unsigned short As[64 * 64];
    __shared__ alignas(16) unsigned short Bs[64 * 64];
    const int e = blockIdx.z;
    const int Te = cnt[e];
    const int m0 = blockIdx.x * 64;
    if (m0 >= Te) return;
    const int n0 = blockIdx.y * 64;
    const int tid = threadIdx.x, lane = tid & 63, w = tid >> 6;
    const int wr = w >> 1, wc = w & 1;

    const int r0 = tid >> 3, r1 = 32 + (tid >> 3);
    const int kc = tid & 7;
    const int kA0 = (kc ^ (r0 & 7)) * 8;
    const int kA1 = (kc ^ (r1 & 7)) * 8;
    const unsigned short* Ab = act_r + (size_t)e * 2048 * 768;
    const unsigned short* Bb = W2b + (size_t)e * 1024 * 768;

    f32x4 acc[2][2];
    for (int i = 0; i < 2; i++)
        for (int j = 0; j < 2; j++) acc[i][j] = (f32x4){0.f, 0.f, 0.f, 0.f};

    for (int k0 = 0; k0 < 768; k0 += 64) {
        ldst16(Ab + (size_t)(m0 + r0) * 768 + k0 + kA0, As + tid * 8);
        ldst16(Ab + (size_t)(m0 + r1) * 768 + k0 + kA1, As + (256 + tid) * 8);
        ldst16(Bb + (size_t)(n0 + r0) * 768 + k0 + kA0, Bs + tid * 8);
        ldst16(Bb + (size_t)(n0 + r1) * 768 + k0 + kA1, Bs + (256 + tid) * 8);
        __syncthreads();
        for (int kh = 0; kh < 2; kh++) {
            const int cq = kh * 4 + (lane >> 4);
            bf16x8 a[2], b[2];
            for (int i = 0; i < 2; i++) {
                int r = 32 * wr + 16 * i + (lane & 15);
                a[i] = *(const bf16x8*)&As[r * 64 + ((cq ^ (r & 7)) << 3)];
            }
            for (int j = 0; j < 2; j++) {
                int r = 32 * wc + 16 * j + (lane & 15);
                b[j] = *(const bf16x8*)&Bs[r * 64 + ((cq ^ (r & 7)) << 3)];
            }
            for (int i = 0; i < 2; i++)
                for (int j = 0; j < 2; j++)
                    acc[i][j] = __builtin_amdgcn_mfma_f32_16x16x32_bf16(a[i], b[j], acc[i][j], 0, 0, 0);
        }
        __syncthreads();
    }

    for (int i = 0; i < 2; i++)
        for (int r = 0; r < 4; r++) {
            int irow = m0 + 32 * wr + 16 * i + ((lane >> 4) << 2) + r;
            if (irow >= Te) continue;
            int pair = tokslot[e * 2048 + irow];
            for (int j = 0; j < 2; j++)
                part[(size_t)pair * 1024 + n0 + 32 * wc + 16 * j + (lane & 15)] = acc[i][j][r];
        }
}

// ---------------- shared fc2 (dense) + final combine ----------------
// tile 64x64, BK=64, K=1536; out = shared + part[t][0] + part[t][1]
__global__ __launch_bounds__(256) void k_fc2s(const unsigned short* __restrict__ act_s,
                                              const unsigned short* __restrict__ Ws2b,
                                              const float* __restrict__ part,
                                              float* __restrict__ out) {
    __shared__ alignas(16) unsigned short As[64 * 64];
    __shared__ alignas(16) unsigned short Bs[64 * 64];
    const int m0 = blockIdx.x * 64, n0 = blockIdx.y * 64;
    const int tid = threadIdx.x, lane = tid & 63, w = tid >> 6;
    const int wr = w >> 1, wc = w & 1;

    const int r0 = tid >> 3, r1 = 32 + (tid >> 3);
    const int kc = tid & 7;
    const int kA0 = (kc ^ (r0 & 7)) * 8;
    const int kA1 = (kc ^ (r1 & 7)) * 8;

    f32x4 acc[2][2];
    for (int i = 0; i < 2; i++)
        for (int j = 0; j < 2; j++) acc[i][j] = (f32x4){0.f, 0.f, 0.f, 0.f};

    for (int k0 = 0; k0 < 1536; k0 += 64) {
        ldst16(act_s + (size_t)(m0 + r0) * 1536 + k0 + kA0, As + tid * 8);
        ldst16(act_s + (size_t)(m0 + r1) * 1536 + k0 + kA1, As + (256 + tid) * 8);
        ldst16(Ws2b + (size_t)(n0 + r0) * 1536 + k0 + kA0, Bs + tid * 8);
        ldst16(Ws2b + (size_t)(n0 + r1) * 1536 + k0 + kA1, Bs + (256 + tid) * 8);
        __syncthreads();
        for (int kh = 0; kh < 2; kh++) {
            const int cq = kh * 4 + (lane >> 4);
            bf16x8 a[2], b[2];
            for (int i = 0; i < 2; i++) {
                int r = 32 * wr + 16 * i + (lane & 15);
                a[i] = *(const bf16x8*)&As[r * 64 + ((cq ^ (r & 7)) << 3)];
            }
            for (int j = 0; j < 2; j++) {
                int r = 32 * wc + 16 * j + (lane & 15);
                b[j] = *(const bf16x8*)&Bs[r * 64 + ((cq ^ (r & 7)) << 3)];
            }
            for (int i = 0; i < 2; i++)
                for (int j = 0; j < 2; j++)
                    acc[i][j] = __builtin_amdgcn_mfma_f32_16x16x32_bf16(a[i], b[j], acc[i][j], 0, 0, 0);
        }
        __syncthreads();
    }

    for (int i = 0; i < 2; i++)
        for (int r = 0; r < 4; r++) {
            int t = m0 + 32 * wr + 16 * i + ((lane >> 4) << 2) + r;
            for (int j = 0; j < 2; j++) {
                int col = n0 + 32 * wc + 16 * j + (lane & 15);
                out[(size_t)t * 1024 + col] = acc[i][j][r]
                    + part[(size_t)(t * 2) * 1024 + col]
                    + part[(size_t)(t * 2 + 1) * 1024 + col];
            }
        }
}

extern "C" void kernel_launch(void* const* d_in, const int* in_sizes, int n_in,
                              void* d_out, int out_size, void* d_ws, size_t ws_size,
                              hipStream_t stream) {
    const float* x   = (const float*)d_in[0];
    const float* gw  = (const float*)d_in[1];
    const float* W1  = (const float*)d_in[2];
    const float* W2  = (const float*)d_in[3];
    const float* Ws1 = (const float*)d_in[4];
    const float* Ws2 = (const float*)d_in[5];
    float* out = (float*)d_out;

    char* ws = (char*)d_ws;
    unsigned short* xb    = (unsigned short*)(ws + 0);          //  4,194,304  (2048x1024)
    unsigned short* W1b   = (unsigned short*)(ws + 4194304);    // 25,165,824  (8x1536x1024)
    unsigned short* Ws1b  = (unsigned short*)(ws + 29360128);   //  6,291,456  (3072x1024)
    unsigned short* W2b   = (unsigned short*)(ws + 35651584);   // 12,582,912  (8x1024x768)
    unsigned short* Ws2b  = (unsigned short*)(ws + 48234496);   //  3,145,728  (1024x1536)
    unsigned short* act_r = (unsigned short*)(ws + 51380224);   // 25,165,824  (8x2048x768)
    unsigned short* act_s = (unsigned short*)(ws + 76546048);   //  6,291,456  (2048x1536)
    float*          part  = (float*)(ws + 82837504);            // 16,777,216  (2048x2x1024)
    int*            topk_e  = (int*)(ws + 99614720);            //     16,384
    float*          topk_w  = (float*)(ws + 99631104);          //     16,384
    int*            tokslot = (int*)(ws + 99647488);            //     65,536
    float*          wroute  = (float*)(ws + 99713024);          //     65,536
    int*            cnt     = (int*)(ws + 99778560);            //         32

    k_conv<<<12544, 256, 0, stream>>>(x, W1, Ws1, W2, Ws2, xb, W1b, Ws1b, W2b, Ws2b);
    k_gate<<<2048, 256, 0, stream>>>(x, gw, topk_e, topk_w);
    k_sort<<<1, 256, 0, stream>>>(topk_e, topk_w, tokslot, wroute, cnt);
    k_fc1r<<<dim3(16, 12, 8), 256, 0, stream>>>(xb, W1b, tokslot, wroute, cnt, act_r);
    k_fc1s<<<dim3(16, 24), 256, 0, stream>>>(xb, Ws1b, act_s);
    k_fc2r<<<dim3(32, 16, 8), 256, 0, stream>>>(act_r, W2b, tokslot, cnt, part);
    k_fc2s<<<dim3(32, 16), 256, 0, stream>>>(act_s, Ws2b, part, out);
}

// Round 3
// 250.664 us; speedup vs baseline: 1.2988x; 1.2470x over previous
//
#include <hip/hip_runtime.h>
#include <hip/hip_bf16.h>

// Sparse MoE: T=2048, D=1024, E=8 routed (H=768, top-2), shared GatedMLP (1536 hidden).
// R3: dense flattened grids (no CU resonance from early-exit blocks), unified fc1
// (routed+shared), fc2 shared writes out then routed atomicAdds into it.

typedef short bf16x8 __attribute__((ext_vector_type(8)));
typedef float f32x4 __attribute__((ext_vector_type(4)));

__device__ __forceinline__ unsigned short f2b(float f) {
    __hip_bfloat16 h = __float2bfloat16(f);
    return *reinterpret_cast<unsigned short*>(&h);
}

__device__ __forceinline__ void ldst16(const unsigned short* g, unsigned short* l) {
    __builtin_amdgcn_global_load_lds(
        (const __attribute__((address_space(1))) unsigned int*)g,
        (__attribute__((address_space(3))) unsigned int*)l, 16, 0, 0);
}

__device__ __forceinline__ void cvt8(const float* s, unsigned short* d, int j) {
    const float4* sp = reinterpret_cast<const float4*>(s) + (size_t)j * 2;
    float4 v0 = sp[0], v1 = sp[1];
    union { unsigned short u[8]; uint4 v; } o;
    o.u[0]=f2b(v0.x); o.u[1]=f2b(v0.y); o.u[2]=f2b(v0.z); o.u[3]=f2b(v0.w);
    o.u[4]=f2b(v1.x); o.u[5]=f2b(v1.y); o.u[6]=f2b(v1.z); o.u[7]=f2b(v1.w);
    *(reinterpret_cast<uint4*>(d) + j) = o.v;
}

// ---------------- one-shot fp32->bf16 conversion ----------------
__global__ __launch_bounds__(256) void k_conv(const float* __restrict__ x,
                                              const float* __restrict__ W1,
                                              const float* __restrict__ Ws1,
                                              const float* __restrict__ W2,
                                              const float* __restrict__ Ws2,
                                              unsigned short* __restrict__ xb,
                                              unsigned short* __restrict__ W1b,
                                              unsigned short* __restrict__ Ws1b,
                                              unsigned short* __restrict__ W2b,
                                              unsigned short* __restrict__ Ws2b) {
    int i = blockIdx.x * 256 + threadIdx.x;
    if (i < 262144)        cvt8(x,   xb,   i);
    else if (i < 1835008)  cvt8(W1,  W1b,  i - 262144);
    else if (i < 2228224)  cvt8(Ws1, Ws1b, i - 1835008);
    else if (i < 3014656)  cvt8(W2,  W2b,  i - 2228224);
    else if (i < 3211264)  cvt8(Ws2, Ws2b, i - 3014656);
}

// ---------------- gate: fp32 logits, softmax, top-2 ----------------
__global__ __launch_bounds__(256) void k_gate(const float* __restrict__ x,
                                              const float* __restrict__ gw,
                                              int* __restrict__ topk_e,
                                              float* __restrict__ topk_w) {
    int t = blockIdx.x;
    int lane = threadIdx.x & 63, w = threadIdx.x >> 6;
    __shared__ float sc[8];
    const float* xr = x + (size_t)t * 1024;
    for (int e = w; e < 8; e += 4) {
        const float* g = gw + (size_t)e * 1024;
        float s = 0.f;
        for (int k = lane; k < 1024; k += 64) s += xr[k] * g[k];
        for (int off = 32; off > 0; off >>= 1) s += __shfl_down(s, off, 64);
        if (lane == 0) sc[e] = s;
    }
    __syncthreads();
    if (threadIdx.x == 0) {
        float m = sc[0];
        for (int e = 1; e < 8; e++) m = fmaxf(m, sc[e]);
        float ex[8], sum = 0.f;
        for (int e = 0; e < 8; e++) { ex[e] = expf(sc[e] - m); sum += ex[e]; }
        float inv = 1.f / sum;
        int i1 = 0;
        for (int e = 1; e < 8; e++) if (sc[e] > sc[i1]) i1 = e;
        int i2 = -1; float s2 = -1e30f;
        for (int e = 0; e < 8; e++) if (e != i1 && sc[e] > s2) { s2 = sc[e]; i2 = e; }
        topk_e[t * 2]     = i1; topk_w[t * 2]     = ex[i1] * inv;
        topk_e[t * 2 + 1] = i2; topk_w[t * 2 + 1] = ex[i2] * inv;
    }
}

// ---------------- counting sort into per-expert lists ----------------
__global__ __launch_bounds__(256) void k_sort(const int* __restrict__ topk_e,
                                              const float* __restrict__ topk_w,
                                              int* __restrict__ tokslot,
                                              float* __restrict__ wroute,
                                              int* __restrict__ cnt) {
    __shared__ int lcnt[8], lcur[8];
    int tid = threadIdx.x;
    if (tid < 8) { lcnt[tid] = 0; lcur[tid] = 0; }
    __syncthreads();
    for (int i = tid; i < 4096; i += 256) atomicAdd(&lcnt[topk_e[i]], 1);
    __syncthreads();
    if (tid < 8) cnt[tid] = lcnt[tid];
    for (int i = tid; i < 4096; i += 256) {
        int e = topk_e[i];
        int pos = atomicAdd(&lcur[e], 1);
        tokslot[e * 2048 + pos] = i;          // i = t*2 + slot
        wroute[e * 2048 + pos]  = topk_w[i];
    }
}

// ---------------- unified fc1: routed (gathered) + shared, fused silu ----------------
// M=64 tokens x N=64 h-cols, BK=64. B stages 128 rows (64 y + 64 g).
// Grid: [0,864) routed (72 m-tiles x 12 h-tiles, ht fastest), [864,1632) shared.
__global__ __launch_bounds__(256) void k_fc1u(const unsigned short* __restrict__ xb,
                                              const unsigned short* __restrict__ W1b,
                                              const unsigned short* __restrict__ Ws1b,
                                              const int* __restrict__ tokslot,
                                              const float* __restrict__ wroute,
                                              const int* __restrict__ cnt,
                                              unsigned short* __restrict__ act_r,
                                              unsigned short* __restrict__ act_s) {
    __shared__ alignas(16) unsigned short As[64 * 64];    // 8KB
    __shared__ alignas(16) unsigned short Bs[128 * 64];   // 16KB
    const int tid = threadIdx.x, lane = tid & 63, w = tid >> 6;
    const int wr = w >> 1, wc = w & 1;
    const int bid = blockIdx.x;

    int routed, e = 0, m0, h0, gOff, Te;
    const unsigned short* Bp;
    if (bid < 864) {
        int ht = bid % 12, mt = bid / 12;
        int pre = 0, sel = -1, base = 0;
        for (int ee = 0; ee < 8; ee++) {
            int til = (cnt[ee] + 63) >> 6;
            if (sel < 0 && mt < pre + til) { sel = ee; base = pre; }
            pre += til;
        }
        if (sel < 0) return;                  // contiguous-at-end empties only
        routed = 1; e = sel; m0 = (mt - base) * 64; h0 = ht * 64;
        Bp = W1b + (size_t)e * 1536 * 1024; gOff = 768; Te = cnt[e];
    } else {
        int sid = bid - 864;
        routed = 0; m0 = (sid / 24) * 64; h0 = (sid % 24) * 64;
        Bp = Ws1b; gOff = 1536; Te = 2048;
    }

    const int arow0 = tid >> 3, arow1 = 32 + (tid >> 3);
    const int kc = tid & 7;
    const int kA0 = (kc ^ (arow0 & 7)) * 8;
    const int kA1 = (kc ^ (arow1 & 7)) * 8;
    int t0, t1;
    if (routed) {
        t0 = (m0 + arow0 < Te) ? (tokslot[e * 2048 + m0 + arow0] >> 1) : 0;
        t1 = (m0 + arow1 < Te) ? (tokslot[e * 2048 + m0 + arow1] >> 1) : 0;
    } else { t0 = m0 + arow0; t1 = m0 + arow1; }

    // B rows: q=0,1 -> y rows 0..63 ; q=2,3 -> g rows 64..127
    size_t bsrc[4]; int bkof[4];
    for (int q = 0; q < 4; q++) {
        int row = q * 32 + (tid >> 3);
        int grow = (row < 64) ? (h0 + row) : (gOff + h0 + row - 64);
        bsrc[q] = (size_t)grow * 1024;
        bkof[q] = (kc ^ (row & 7)) * 8;
    }

    f32x4 accy[2][2], accg[2][2];
    for (int i = 0; i < 2; i++)
        for (int j = 0; j < 2; j++) {
            accy[i][j] = (f32x4){0.f, 0.f, 0.f, 0.f};
            accg[i][j] = (f32x4){0.f, 0.f, 0.f, 0.f};
        }

    for (int k0 = 0; k0 < 1024; k0 += 64) {
        ldst16(xb + (size_t)t0 * 1024 + k0 + kA0, As + tid * 8);
        ldst16(xb + (size_t)t1 * 1024 + k0 + kA1, As + (256 + tid) * 8);
        for (int q = 0; q < 4; q++)
            ldst16(Bp + bsrc[q] + k0 + bkof[q], Bs + (q * 256 + tid) * 8);
        __syncthreads();
        for (int kh = 0; kh < 2; kh++) {
            const int cq = kh * 4 + (lane >> 4);
            bf16x8 a[2], by[2], bg[2];
            for (int i = 0; i < 2; i++) {
                int r = 32 * wr + 16 * i + (lane & 15);
                a[i] = *(const bf16x8*)&As[r * 64 + ((cq ^ (r & 7)) << 3)];
            }
            for (int j = 0; j < 2; j++) {
                int ry = 32 * wc + 16 * j + (lane & 15);
                by[j] = *(const bf16x8*)&Bs[ry * 64 + ((cq ^ (ry & 7)) << 3)];
                int rg = 64 + ry;
                bg[j] = *(const bf16x8*)&Bs[rg * 64 + ((cq ^ (rg & 7)) << 3)];
            }
            for (int i = 0; i < 2; i++)
                for (int j = 0; j < 2; j++) {
                    accy[i][j] = __builtin_amdgcn_mfma_f32_16x16x32_bf16(a[i], by[j], accy[i][j], 0, 0, 0);
                    accg[i][j] = __builtin_amdgcn_mfma_f32_16x16x32_bf16(a[i], bg[j], accg[i][j], 0, 0, 0);
                }
        }
        __syncthreads();
    }

    for (int i = 0; i < 2; i++)
        for (int r = 0; r < 4; r++) {
            int irow = m0 + 32 * wr + 16 * i + ((lane >> 4) << 2) + r;
            if (irow >= Te) continue;
            float sw = routed ? wroute[e * 2048 + irow] : 1.0f;
            for (int j = 0; j < 2; j++) {
                float y = accy[i][j][r], g = accg[i][j][r];
                float sg = g / (1.0f + __expf(-g));
                int col = h0 + 32 * wc + 16 * j + (lane & 15);
                if (routed)
                    act_r[((size_t)e * 2048 + irow) * 768 + col] = f2b(sw * y * sg);
                else
                    act_s[(size_t)irow * 1536 + col] = f2b(y * sg);
            }
        }
}

// ---------------- shared fc2 (dense): out = act_s @ Ws2^T ----------------
// 64x64 tile, BK=64, K=1536. Writes out (runs BEFORE k_fc2r's atomics).
__global__ __launch_bounds__(256) void k_fc2s(const unsigned short* __restrict__ act_s,
                                              const unsigned short* __restrict__ Ws2b,
                                              float* __restrict__ out) {
    __shared__ alignas(16) unsigned short As[64 * 64];
    __shared__ alignas(16) unsigned short Bs[64 * 64];
    const int m0 = blockIdx.x * 64, n0 = blockIdx.y * 64;
    const int tid = threadIdx.x, lane = tid & 63, w = tid >> 6;
    const int wr = w >> 1, wc = w & 1;
    const int kc = tid & 7;

    size_t asrc[2], bsrc[2]; int kof[2];
    for (int q = 0; q < 2; q++) {
        int row = q * 32 + (tid >> 3);
        kof[q] = (kc ^ (row & 7)) * 8;
        asrc[q] = (size_t)(m0 + row) * 1536;
        bsrc[q] = (size_t)(n0 + row) * 1536;
    }

    f32x4 acc[2][2];
    for (int i = 0; i < 2; i++)
        for (int j = 0; j < 2; j++) acc[i][j] = (f32x4){0.f, 0.f, 0.f, 0.f};

    for (int k0 = 0; k0 < 1536; k0 += 64) {
        for (int q = 0; q < 2; q++) {
            ldst16(act_s + asrc[q] + k0 + kof[q], As + (q * 256 + tid) * 8);
            ldst16(Ws2b  + bsrc[q] + k0 + kof[q], Bs + (q * 256 + tid) * 8);
        }
        __syncthreads();
        for (int kh = 0; kh < 2; kh++) {
            const int cq = kh * 4 + (lane >> 4);
            bf16x8 a[2], b[2];
            for (int i = 0; i < 2; i++) {
                int r = 32 * wr + 16 * i + (lane & 15);
                a[i] = *(const bf16x8*)&As[r * 64 + ((cq ^ (r & 7)) << 3)];
            }
            for (int j = 0; j < 2; j++) {
                int r = 32 * wc + 16 * j + (lane & 15);
                b[j] = *(const bf16x8*)&Bs[r * 64 + ((cq ^ (r & 7)) << 3)];
            }
            for (int i = 0; i < 2; i++)
                for (int j = 0; j < 2; j++)
                    acc[i][j] = __builtin_amdgcn_mfma_f32_16x16x32_bf16(a[i], b[j], acc[i][j], 0, 0, 0);
        }
        __syncthreads();
    }

    for (int i = 0; i < 2; i++)
        for (int r = 0; r < 4; r++) {
            int t = m0 + 32 * wr + 16 * i + ((lane >> 4) << 2) + r;
            for (int j = 0; j < 2; j++) {
                int col = n0 + 32 * wc + 16 * j + (lane & 15);
                out[(size_t)t * 1024 + col] = acc[i][j][r];
            }
        }
}

// ---------------- routed fc2: per-expert GEMM, atomicAdd into out ----------------
// Flattened dense grid: bid = mt*16 + nt, mt over expert m-tiles (64 rows), K=768.
__global__ __launch_bounds__(256) void k_fc2r(const unsigned short* __restrict__ act_r,
                                              const unsigned short* __restrict__ W2b,
                                              const int* __restrict__ tokslot,
                                              const int* __restrict__ cnt,
                                              float* __restrict__ out) {
    __shared__ alignas(16) unsigned short As[64 * 64];
    __shared__ alignas(16) unsigned short Bs[64 * 64];
    const int tid = threadIdx.x, lane = tid & 63, w = tid >> 6;
    const int wr = w >> 1, wc = w & 1;
    const int nt = blockIdx.x & 15, mt = blockIdx.x >> 4;

    int pre = 0, sel = -1, base = 0;
    for (int ee = 0; ee < 8; ee++) {
        int til = (cnt[ee] + 63) >> 6;
        if (sel < 0 && mt < pre + til) { sel = ee; base = pre; }
        pre += til;
    }
    if (sel < 0) return;
    const int e = sel, m0 = (mt - base) * 64, n0 = nt * 64;
    const int Te = cnt[e];
    const unsigned short* Ab = act_r + (size_t)e * 2048 * 768;
    const unsigned short* Bb = W2b + (size_t)e * 1024 * 768;
    const int kc = tid & 7;

    size_t asrc[2], bsrc[2]; int kof[2];
    for (int q = 0; q < 2; q++) {
        int row = q * 32 + (tid >> 3);
        kof[q] = (kc ^ (row & 7)) * 8;
        asrc[q] = (size_t)(m0 + row) * 768;
        bsrc[q] = (size_t)(n0 + row) * 768;
    }

    f32x4 acc[2][2];
    for (int i = 0; i < 2; i++)
        for (int j = 0; j < 2; j++) acc[i][j] = (f32x4){0.f, 0.f, 0.f, 0.f};

    for (int k0 = 0; k0 < 768; k0 += 64) {
        for (int q = 0; q < 2; q++) {
            ldst16(Ab + asrc[q] + k0 + kof[q], As + (q * 256 + tid) * 8);
            ldst16(Bb + bsrc[q] + k0 + kof[q], Bs + (q * 256 + tid) * 8);
        }
        __syncthreads();
        for (int kh = 0; kh < 2; kh++) {
            const int cq = kh * 4 + (lane >> 4);
            bf16x8 a[2], b[2];
            for (int i = 0; i < 2; i++) {
                int r = 32 * wr + 16 * i + (lane & 15);
                a[i] = *(const bf16x8*)&As[r * 64 + ((cq ^ (r & 7)) << 3)];
            }
            for (int j = 0; j < 2; j++) {
                int r = 32 * wc + 16 * j + (lane & 15);
                b[j] = *(const bf16x8*)&Bs[r * 64 + ((cq ^ (r & 7)) << 3)];
            }
            for (int i = 0; i < 2; i++)
                for (int j = 0; j < 2; j++)
                    acc[i][j] = __builtin_amdgcn_mfma_f32_16x16x32_bf16(a[i], b[j], acc[i][j], 0, 0, 0);
        }
        __syncthreads();
    }

    for (int i = 0; i < 2; i++)
        for (int r = 0; r < 4; r++) {
            int irow = m0 + 32 * wr + 16 * i + ((lane >> 4) << 2) + r;
            if (irow >= Te) continue;
            int t = tokslot[e * 2048 + irow] >> 1;
            for (int j = 0; j < 2; j++) {
                int col = n0 + 32 * wc + 16 * j + (lane & 15);
                atomicAdd(out + (size_t)t * 1024 + col, acc[i][j][r]);
            }
        }
}

extern "C" void kernel_launch(void* const* d_in, const int* in_sizes, int n_in,
                              void* d_out, int out_size, void* d_ws, size_t ws_size,
                              hipStream_t stream) {
    const float* x   = (const float*)d_in[0];
    const float* gw  = (const float*)d_in[1];
    const float* W1  = (const float*)d_in[2];
    const float* W2  = (const float*)d_in[3];
    const float* Ws1 = (const float*)d_in[4];
    const float* Ws2 = (const float*)d_in[5];
    float* out = (float*)d_out;

    char* ws = (char*)d_ws;
    unsigned short* xb    = (unsigned short*)(ws + 0);          //  4,194,304
    unsigned short* W1b   = (unsigned short*)(ws + 4194304);    // 25,165,824
    unsigned short* Ws1b  = (unsigned short*)(ws + 29360128);   //  6,291,456
    unsigned short* W2b   = (unsigned short*)(ws + 35651584);   // 12,582,912
    unsigned short* Ws2b  = (unsigned short*)(ws + 48234496);   //  3,145,728
    unsigned short* act_r = (unsigned short*)(ws + 51380224);   // 25,165,824
    unsigned short* act_s = (unsigned short*)(ws + 76546048);   //  6,291,456
    int*            topk_e  = (int*)(ws + 82837504);            //     16,384
    float*          topk_w  = (float*)(ws + 82853888);          //     16,384
    int*            tokslot = (int*)(ws + 82870272);            //     65,536
    float*          wroute  = (float*)(ws + 82935808);          //     65,536
    int*            cnt     = (int*)(ws + 83001344);            //         32

    k_conv<<<12544, 256, 0, stream>>>(x, W1, Ws1, W2, Ws2, xb, W1b, Ws1b, W2b, Ws2b);
    k_gate<<<2048, 256, 0, stream>>>(x, gw, topk_e, topk_w);
    k_sort<<<1, 256, 0, stream>>>(topk_e, topk_w, tokslot, wroute, cnt);
    k_fc1u<<<1632, 256, 0, stream>>>(xb, W1b, Ws1b, tokslot, wroute, cnt, act_r, act_s);
    k_fc2s<<<dim3(32, 16), 256, 0, stream>>>(act_s, Ws2b, out);
    k_fc2r<<<1152, 256, 0, stream>>>(act_r, W2b, tokslot, cnt, out);
}